// Round 4
// baseline (666.946 us; speedup 1.0000x reference)
//
#include <hip/hip_runtime.h>

// Problem constants (fixed by reference setup_inputs):
//   inputs: [8192, 64] f32, rand: [8192, 64] f32
//   capacity = max(ceil(1.25 * 8192 / 64), 4) = 160
#define S 8192
#define E 64
#define CAP 160
#define ROW (E * CAP)                       // 10240 floats per token row
#define NCHUNK (S / 256)                    // 32 chunks of 256 tokens
static constexpr long long COMB = (long long)S * E * CAP;  // 83,886,080

typedef float f32x4 __attribute__((ext_vector_type(4)));

// --- Kernel 1: per-token router (one wave per token) ----------------------
// argmax (lowest-index tiebreak, matching jnp.argmax), softmax prob at the
// argmax = 1/sum(exp(x-max)), and rand value at the argmax column.
__global__ __launch_bounds__(256) void router_kernel(
    const float* __restrict__ x, const float* __restrict__ rnd,
    int* __restrict__ eidx, float* __restrict__ prob, float* __restrict__ rv)
{
    const int token = blockIdx.x * 4 + (threadIdx.x >> 6);
    const int lane  = threadIdx.x & 63;

    const float v = x[token * E + lane];
    const float r = rnd[token * E + lane];

    float m = v; int ai = lane;
    #pragma unroll
    for (int off = 32; off; off >>= 1) {
        float m2 = __shfl_xor(m, off, 64);
        int   i2 = __shfl_xor(ai, off, 64);
        if (m2 > m || (m2 == m && i2 < ai)) { m = m2; ai = i2; }
    }

    float s = expf(v - m);
    #pragma unroll
    for (int off = 32; off; off >>= 1) s += __shfl_xor(s, off, 64);

    const float ra = __shfl(r, ai, 64);

    if (lane == 0) {
        eidx[token] = ai;
        prob[token] = 1.0f / s;
        rv[token]   = ra;
    }
}

// --- Kernel 2: per-chunk expert histogram (32 blocks) ---------------------
__global__ __launch_bounds__(256) void hist_kernel(
    const int* __restrict__ eidx, int* __restrict__ chunk_hist)
{
    __shared__ int h[E];
    const int b = blockIdx.x;
    if (threadIdx.x < E) h[threadIdx.x] = 0;
    __syncthreads();
    atomicAdd(&h[eidx[b * 256 + threadIdx.x]], 1);
    __syncthreads();
    if (threadIdx.x < E) chunk_hist[b * E + threadIdx.x] = h[threadIdx.x];
}

// --- Kernel 3: slot assignment (32 blocks) --------------------------------
// loc[t] = rank of token t among same-expert tokens by index
//        = (prefix over earlier chunks) + (rank within chunk).
// Writes ofs[t] = e*CAP + loc (or -1 if dropped), counts[e].
// Overflow fallback (count > CAP, NOT triggered for this input: max 152)
// reproduces jax.lax.top_k's (rand desc, index asc) selection exactly.
__global__ __launch_bounds__(256) void rank_kernel(
    const int* __restrict__ eidx, const float* __restrict__ rv,
    const int* __restrict__ chunk_hist,
    int* __restrict__ ofs, int* __restrict__ counts_g)
{
    const int b   = blockIdx.x;
    const int tid = threadIdx.x;
    __shared__ int base[E];
    __shared__ int tot[E];
    __shared__ int le[256];

    if (tid < E) {
        int pre = 0, tt = 0;
        for (int c = 0; c < NCHUNK; ++c) {
            const int v = chunk_hist[c * E + tid];
            if (c < b) pre += v;
            tt += v;
        }
        base[tid] = pre; tot[tid] = tt;
        if (b == 0) counts_g[tid] = tt;
    }
    const int t = b * 256 + tid;
    const int e = eidx[t];
    le[tid] = e;
    __syncthreads();

    int rank = 0;
    for (int j = 0; j < tid; ++j) rank += (le[j] == e);
    int loc = base[e] + rank;

    bool kept = true;
    if (tot[e] > CAP) {   // guarded slow path; never taken for this input
        const float rt = rv[t];
        int better = 0;
        for (int j = 0; j < S; ++j)
            if (eidx[j] == e) {
                const float rj = rv[j];
                if (rj > rt || (rj == rt && j < t)) better++;
            }
        kept = (better < CAP);
        if (kept) {
            int l = 0;
            for (int j = 0; j < t; ++j)
                if (eidx[j] == e) {
                    const float rj = rv[j];
                    int bj = 0;
                    for (int k = 0; k < S; ++k)
                        if (eidx[k] == e) {
                            const float rk = rv[k];
                            if (rk > rj || (rk == rj && k < j)) bj++;
                        }
                    if (bj < CAP) l++;
                }
            loc = l;
        }
    }
    ofs[t] = kept ? (e * CAP + loc) : -1;
}

// --- Kernel 4: fused zero-fill + scatter ----------------------------------
// Grid = 2*S blocks. Block b < S fills combine_weights row b (40 KB
// contiguous); block b >= S fills sec_mask row b-S. Plain (cached) float4
// stores — same access shape as rocclr's 6.2 TB/s fillBuffer. Each output
// byte written exactly once.
__global__ __launch_bounds__(256) void fill_scatter_kernel(
    const int* __restrict__ ofs, const float* __restrict__ prob,
    const int* __restrict__ counts, float* __restrict__ out)
{
    const int b    = blockIdx.x;
    const int tid  = threadIdx.x;
    const bool msk = (b >= S);
    const int t    = msk ? b - S : b;
    const int o    = ofs[t];                      // wave-uniform L1 broadcast
    const float v  = msk ? 1.0f : prob[t];

    f32x4* __restrict__ dst =
        (f32x4*)(out + (msk ? (size_t)COMB : (size_t)0) + (size_t)t * ROW);

    #pragma unroll
    for (int k = 0; k < ROW / 4 / 256; ++k) {   // 10 iterations
        const int c4  = k * 256 + tid;
        const int col = c4 * 4;
        f32x4 z;
        z.x = (o == col + 0) ? v : 0.0f;
        z.y = (o == col + 1) ? v : 0.0f;
        z.z = (o == col + 2) ? v : 0.0f;
        z.w = (o == col + 3) ? v : 0.0f;
        dst[c4] = z;
    }

    if (b == 0 && tid < E)
        out[2 * COMB + tid] = (float)counts[tid];
}

extern "C" void kernel_launch(void* const* d_in, const int* in_sizes, int n_in,
                              void* d_out, int out_size, void* d_ws, size_t ws_size,
                              hipStream_t stream)
{
    const float* inputs = (const float*)d_in[0];
    const float* rnd    = (const float*)d_in[1];
    float* out = (float*)d_out;

    // workspace layout (all int32/f32, S=8192):
    //   eidx[S] | prob[S] | rv[S] | ofs[S] | chunk_hist[32*64] | counts[64]
    char* w = (char*)d_ws;
    int*   eidx  = (int*)w;                          w += S * 4;
    float* prob  = (float*)w;                        w += S * 4;
    float* rv    = (float*)w;                        w += S * 4;
    int*   ofs   = (int*)w;                          w += S * 4;
    int*   chist = (int*)w;                          w += NCHUNK * E * 4;
    int*   cnts  = (int*)w;

    router_kernel<<<S / 4, 256, 0, stream>>>(inputs, rnd, eidx, prob, rv);
    hist_kernel<<<NCHUNK, 256, 0, stream>>>(eidx, chist);
    rank_kernel<<<NCHUNK, 256, 0, stream>>>(eidx, rv, chist, ofs, cnts);
    fill_scatter_kernel<<<2 * S, 256, 0, stream>>>(ofs, prob, cnts, out);
}